// Round 6
// baseline (228.138 us; speedup 1.0000x reference)
//
#include <hip/hip_runtime.h>
#include <math.h>

#define N_NODES 50000
#define N_EDGES 800000
#define CH 128
#define CAP 48   // slots per node; deg ~ Poisson(16), P(deg>=48) ~ 1e-10
#define SCAT_BLOCKS ((N_EDGES + 255) / 256)    // 3125
#define GEMM_BLOCKS ((N_NODES + 127) / 128)    // 391 (128 rows/block, 512 thr)

typedef __attribute__((ext_vector_type(8))) short short8;
typedef __attribute__((ext_vector_type(4))) float f32x4;
union FragU { uint4 u; short8 s; };

// RNE-pack two fp32 into (lo,hi) bf16 halves of a uint.
__device__ __forceinline__ unsigned pack_bf16(float a, float b) {
    unsigned ua = __float_as_uint(a);
    unsigned ub = __float_as_uint(b);
    ua += 0x7FFFu + ((ua >> 16) & 1u);
    ub += 0x7FFFu + ((ub >> 16) & 1u);
    return (ua >> 16) | (ub & 0xFFFF0000u);
}

// ---------------------------------------------------------------------------
// prep_pack: swizzle W_l,W_r (fp32 [out][in]) into MFMA B-fragment-ordered
// bf16 (layout proven round 7). Also zeroes counts (folds the memset dispatch).
__global__ __launch_bounds__(256) void prep_pack_kernel(
    const float* __restrict__ W_l, const float* __restrict__ W_r,
    uint4* __restrict__ Wf4, int* __restrict__ counts)
{
    int tid = blockIdx.x * 256 + threadIdx.x;   // grid 64 blocks -> 16384 threads
    if (tid < 2 * 8 * 4 * 64) {
        int lane  = tid & 63;
        int chunk = (tid >> 6) & 3;
        int tile  = (tid >> 8) & 7;
        int mat   = tid >> 11;
        const float* W = mat ? W_r : W_l;
        int n  = tile * 16 + (lane & 15);
        int k0 = chunk * 32 + (lane >> 4) * 8;
        const float* wp = W + n * CH + k0;
        float4 a = *(const float4*)wp;
        float4 b = *(const float4*)(wp + 4);
        uint4 p;
        p.x = pack_bf16(a.x, a.y);
        p.y = pack_bf16(a.z, a.w);
        p.z = pack_bf16(b.x, b.y);
        p.w = pack_bf16(b.z, b.w);
        Wf4[tid] = p;
    }
    for (int i = tid; i < N_NODES; i += 64 * 256) counts[i] = 0;
}

// ---------------------------------------------------------------------------
// Scatter (simplest proven form: device-scope atomicAdd + cap-slot records;
// rounds 0-4 showed all scatter variants equal).
__global__ __launch_bounds__(256) void scatter_kernel(
    const int* __restrict__ src, const int* __restrict__ dst,
    const float* __restrict__ env,
    int* __restrict__ counts, unsigned* __restrict__ recs)
{
    int i = blockIdx.x * 256 + threadIdx.x;
    if (i < N_EDGES) {
        int d = dst[i];
        int rank = atomicAdd(&counts[d], 1);
        if (rank < CAP) {
            unsigned ev = __float_as_uint(env[i] + 1e-7f);
            ev += 0x7FFFu + ((ev >> 16) & 1u);     // RNE to bf16
            recs[d * CAP + rank] = (unsigned)src[i] | (ev & 0xFFFF0000u);
        }
    }
}

// ---------------------------------------------------------------------------
// MFMA GEMM: g_l(bf16) = q@W_l^T, g_r(fp32) = q@W_r^T. Wf4 staged in LDS.
__global__ __launch_bounds__(512) void gemm_kernel(
    const float* __restrict__ q, const uint4* __restrict__ Wf4,
    unsigned short* __restrict__ g_l16, float* __restrict__ g_r)
{
    __shared__ uint4 sW[4096];   // 64 KB: both matrices, fragment-ordered
    for (int i = threadIdx.x; i < 4096; i += 512) sW[i] = Wf4[i];

    const int wv   = threadIdx.x >> 6;      // 0..7
    const int lane = threadIdx.x & 63;
    const int m    = lane & 15;
    const int quad = lane >> 4;
    const int row0 = blockIdx.x * 128 + wv * 16;

    int arow = row0 + m;
    if (arow >= N_NODES) arow = N_NODES - 1;   // clamp (stores guarded)
    const float* qr = q + (size_t)arow * CH + quad * 8;

    FragU A[4];
    #pragma unroll
    for (int c = 0; c < 4; ++c) {
        float4 x = *(const float4*)(qr + c * 32);
        float4 y = *(const float4*)(qr + c * 32 + 4);
        A[c].u.x = pack_bf16(x.x, x.y);
        A[c].u.y = pack_bf16(x.z, x.w);
        A[c].u.z = pack_bf16(y.x, y.y);
        A[c].u.w = pack_bf16(y.z, y.w);
    }

    __syncthreads();

    for (int mat = 0; mat < 2; ++mat) {
        for (int tile = 0; tile < 8; ++tile) {
            f32x4 acc = {0.f, 0.f, 0.f, 0.f};
            const uint4* bp = sW + (size_t)(mat * 8 + tile) * 256;
            #pragma unroll
            for (int c = 0; c < 4; ++c) {
                FragU B; B.u = bp[c * 64 + lane];
                acc = __builtin_amdgcn_mfma_f32_16x16x32_bf16(A[c].s, B.s, acc, 0, 0, 0);
            }
            int col = tile * 16 + m;
            #pragma unroll
            for (int r = 0; r < 4; ++r) {
                int rowg = row0 + quad * 4 + r;
                if (rowg < N_NODES) {
                    if (mat == 0) {
                        unsigned u = __float_as_uint(acc[r]);
                        u += 0x7FFFu + ((u >> 16) & 1u);
                        g_l16[(size_t)rowg * CH + col] = (unsigned short)(u >> 16);
                    } else {
                        g_r[(size_t)rowg * CH + col] = acc[r];
                    }
                }
            }
        }
    }
}

// ---------------------------------------------------------------------------
// One wave per node, quarter-wave (16 lanes x 8 ch) per edge.
// V3 (round-5 post-mortem: 57.5us, VALUBusy 85% but ~20us of issue work ->
// latency-bound on the serial per-group tail: 4 dependent shfl_xor + exp +
// acc-fma, ONE chain per wave). Fix: process TWO groups (8 edges) per
// iteration with fully independent silu->reduce->exp chains; the compiler
// interleaves them, hiding each chain's cross-lane latency under the other's
// VALU. Gathers prefetched one pair-iteration ahead (as before).
__global__ __launch_bounds__(256) void node_attn_kernel(
    const uint4* __restrict__ g_lb4, const float* __restrict__ g_r,
    const float* __restrict__ attn_w,
    const unsigned* __restrict__ recs, const int* __restrict__ counts,
    float* __restrict__ out)
{
    int gid = blockIdx.x * blockDim.x + threadIdx.x;
    int wid = gid >> 6;
    if (wid >= N_NODES) return;
    const int lane = threadIdx.x & 63;
    const int q4 = lane >> 4;    // quarter 0..3: which edge of the group of 4
    const int sl = lane & 15;    // sub-lane: channels sl*8 .. sl*8+7

    int cnt = counts[wid];
    if (cnt > CAP) cnt = CAP;

    float gr[8], aw[8];
    {
        const float4* grp = (const float4*)(g_r + (size_t)wid * CH + sl * 8);
        float4 a = grp[0], b = grp[1];
        gr[0] = a.x; gr[1] = a.y; gr[2] = a.z; gr[3] = a.w;
        gr[4] = b.x; gr[5] = b.y; gr[6] = b.z; gr[7] = b.w;
        const float4* awp = (const float4*)(attn_w + sl * 8);
        float4 c = awp[0], d = awp[1];
        aw[0] = c.x; aw[1] = c.y; aw[2] = c.z; aw[3] = c.w;
        aw[4] = d.x; aw[5] = d.y; aw[6] = d.z; aw[7] = d.w;
    }

    float l = 0.0f;
    float acc[8] = {0.f, 0.f, 0.f, 0.f, 0.f, 0.f, 0.f, 0.f};

    if (cnt > 0) {
        const int clampi = cnt - 1;
        // whole bucket in one coalesced load (lanes >= cnt clamp to last slot)
        unsigned rcl = recs[wid * CAP + min(lane, clampi)];
        const int G = (cnt + 3) >> 2;   // groups of 4 edges

        #define REC_OF(jg, rv) { int e_ = (jg) * 4 + q4; if (e_ > clampi) e_ = clampi; \
                                 rv = __shfl(rcl, e_, 64); }
        #define GATHER(rv) g_lb4[(size_t)((rv) & 0xFFFFu) * (CH / 8) + sl]

        // current pair (r0,g0 | r1,g1), next pair (r2,g2 | r3,g3)
        unsigned r0, r1, r2, r3;
        uint4 g0, g1, g2, g3;
        REC_OF(0, r0); g0 = GATHER(r0);
        REC_OF(1, r1); g1 = GATHER(r1);   // clamped if G==1 (w masks to 0)
        r2 = r0; r3 = r1; g2 = g0; g3 = g1;
        if (G > 2) { REC_OF(2, r2); g2 = GATHER(r2); }
        if (G > 3) { REC_OF(3, r3); g3 = GATHER(r3); }

        for (int j = 0; j < G; j += 2) {
            // prefetch pair j+4 / j+5 (wave-uniform branches)
            unsigned rn0 = r0, rn1 = r1;
            uint4 gn0 = g0, gn1 = g1;
            if (j + 4 < G) { REC_OF(j + 4, rn0); gn0 = GATHER(rn0); }
            if (j + 5 < G) { REC_OF(j + 5, rn1); gn1 = GATHER(rn1); }

            bool a0 = (j * 4 + q4) < cnt;
            bool a1 = ((j + 1) * 4 + q4) < cnt;
            float ev0 = __uint_as_float(r0 & 0xFFFF0000u);
            float ev1 = __uint_as_float(r1 & 0xFFFF0000u);

            float gl0[8], gl1[8];
            gl0[0] = __uint_as_float(g0.x << 16);
            gl0[1] = __uint_as_float(g0.x & 0xFFFF0000u);
            gl0[2] = __uint_as_float(g0.y << 16);
            gl0[3] = __uint_as_float(g0.y & 0xFFFF0000u);
            gl0[4] = __uint_as_float(g0.z << 16);
            gl0[5] = __uint_as_float(g0.z & 0xFFFF0000u);
            gl0[6] = __uint_as_float(g0.w << 16);
            gl0[7] = __uint_as_float(g0.w & 0xFFFF0000u);
            gl1[0] = __uint_as_float(g1.x << 16);
            gl1[1] = __uint_as_float(g1.x & 0xFFFF0000u);
            gl1[2] = __uint_as_float(g1.y << 16);
            gl1[3] = __uint_as_float(g1.y & 0xFFFF0000u);
            gl1[4] = __uint_as_float(g1.z << 16);
            gl1[5] = __uint_as_float(g1.z & 0xFFFF0000u);
            gl1[6] = __uint_as_float(g1.w << 16);
            gl1[7] = __uint_as_float(g1.w & 0xFFFF0000u);

            float p0 = 0.0f, p1 = 0.0f;
            #pragma unroll
            for (int c = 0; c < 8; ++c) {
                float h0 = gl0[c] + gr[c];
                float h1 = gl1[c] + gr[c];
                float s0 = __builtin_amdgcn_rcpf(1.0f + __expf(-h0));
                float s1 = __builtin_amdgcn_rcpf(1.0f + __expf(-h1));
                p0 = fmaf(h0 * aw[c], s0, p0);
                p1 = fmaf(h1 * aw[c], s1, p1);
            }
            // two independent 16-lane reduces; chains interleave -> latency hidden
            #pragma unroll
            for (int o = 1; o <= 8; o <<= 1) {
                p0 += __shfl_xor(p0, o, 64);
                p1 += __shfl_xor(p1, o, 64);
            }

            float w0 = __expf(p0) * (a0 ? ev0 : 0.0f);
            float w1 = __expf(p1) * (a1 ? ev1 : 0.0f);
            l += w0 + w1;
            #pragma unroll
            for (int c = 0; c < 8; ++c)
                acc[c] = fmaf(w0, gl0[c], fmaf(w1, gl1[c], acc[c]));

            r0 = r2; g0 = g2; r1 = r3; g1 = g3;
            r2 = rn0; g2 = gn0; r3 = rn1; g3 = gn1;
        }
        #undef REC_OF
        #undef GATHER
    }

    #pragma unroll
    for (int o = 16; o <= 32; o <<= 1) {
        l += __shfl_xor(l, o, 64);
        #pragma unroll
        for (int c = 0; c < 8; ++c) acc[c] += __shfl_xor(acc[c], o, 64);
    }

    if (q4 == 0) {
        float inv = (l > 0.0f) ? __builtin_amdgcn_rcpf(l) : 0.0f;
        float4 o0 = {acc[0] * inv, acc[1] * inv, acc[2] * inv, acc[3] * inv};
        float4 o1 = {acc[4] * inv, acc[5] * inv, acc[6] * inv, acc[7] * inv};
        float4* op = (float4*)(out + (size_t)wid * CH + sl * 8);
        op[0] = o0;
        op[1] = o1;
    }
}

// ---------------------------------------------------------------------------
extern "C" void kernel_launch(void* const* d_in, const int* in_sizes, int n_in,
                              void* d_out, int out_size, void* d_ws, size_t ws_size,
                              hipStream_t stream)
{
    const float* q      = (const float*)d_in[0];
    // d_in[1]=k, d_in[2]=v : unused (matches reference)
    const float* env    = (const float*)d_in[3];
    const float* W_l    = (const float*)d_in[4];
    const float* W_r    = (const float*)d_in[5];
    const float* attn_w = (const float*)d_in[6];
    const int*   eidx   = (const int*)d_in[7];
    const int* src = eidx;
    const int* dst = eidx + N_EDGES;
    float* out = (float*)d_out;

    float* ws    = (float*)d_ws;
    unsigned* g_lb = (unsigned*)ws;                      // N*CH/2 uints (bf16 pairs)
    float* g_r   = (float*)(g_lb + (size_t)N_NODES * (CH / 2));  // N*CH fp32
    uint4* Wf4   = (uint4*)(g_r + (size_t)N_NODES * CH); // 4096 uint4 = 64 KB
    unsigned* recs = (unsigned*)(Wf4 + 4096);            // N*CAP 4B records (9.6 MB)
    int* counts  = (int*)(recs + (size_t)N_NODES * CAP); // N

    prep_pack_kernel<<<64, 256, 0, stream>>>(W_l, W_r, Wf4, counts);

    scatter_kernel<<<SCAT_BLOCKS, 256, 0, stream>>>(src, dst, env, counts, recs);

    gemm_kernel<<<GEMM_BLOCKS, 512, 0, stream>>>(
        q, Wf4, (unsigned short*)g_lb, g_r);

    int node_wave_blocks = (N_NODES * 64 + 255) / 256;
    node_attn_kernel<<<node_wave_blocks, 256, 0, stream>>>(
        (const uint4*)g_lb, g_r, attn_w, recs, counts, out);
}